// Round 3
// baseline (364.935 us; speedup 1.0000x reference)
//
#include <hip/hip_runtime.h>
#include <stdint.h>

#define T_SEQ 2048
#define DM    2048
#define NH    16
#define NKV   4
#define HD    128
#define MROWS 4096          // B*T
#define NQKV  3072          // 16*128 + 4*128 + 4*128

typedef unsigned short u16;
typedef __bf16 bf16x8 __attribute__((ext_vector_type(8)));
typedef float  f32x4  __attribute__((ext_vector_type(4)));

__device__ __forceinline__ u16 f2b(float f) {
  union { float f; unsigned u; } v; v.f = f;
  return (u16)((v.u + 0x7fffu + ((v.u >> 16) & 1u)) >> 16);
}
__device__ __forceinline__ float b2f(u16 u) {
  union { unsigned u; float f; } v; v.u = ((unsigned)u) << 16;
  return v.f;
}
// async global->LDS, 16B per lane; LDS dest = wave-uniform base + lane*16
__device__ __forceinline__ void gl_lds16(const u16* g, u16* l) {
  __builtin_amdgcn_global_load_lds(
      (__attribute__((address_space(1))) void*)g,
      (__attribute__((address_space(3))) void*)l, 16, 0, 0);
}
__device__ __forceinline__ void storev(float* p, float v) { *p = v; }
__device__ __forceinline__ void storev(u16* p, float v)   { *p = f2b(v); }

// ---- fp32 -> bf16 elementwise (x) ----
__global__ __launch_bounds__(256) void k_cvt_x(const float* __restrict__ x,
                                               u16* __restrict__ o, int n) {
  int i = (blockIdx.x * 256 + threadIdx.x) * 4;
  if (i >= n) return;
  float4 v = *(const float4*)(x + i);
  ushort4 r;
  r.x = f2b(v.x); r.y = f2b(v.y); r.z = f2b(v.z); r.w = f2b(v.w);
  *(ushort4*)(o + i) = r;
}

// ---- W [K][N] fp32 -> Wt [N][K] bf16 (LDS tile transpose) ----
__global__ __launch_bounds__(256) void k_tw(const float* __restrict__ in,
                                            u16* __restrict__ out, int Kd, int Nd) {
  __shared__ float tl[32][33];
  int n0 = blockIdx.x * 32, k0 = blockIdx.y * 32;
  int tx = threadIdx.x, ty = threadIdx.y;
#pragma unroll
  for (int i = 0; i < 32; i += 8)
    tl[ty + i][tx] = in[(long)(k0 + ty + i) * Nd + n0 + tx];
  __syncthreads();
#pragma unroll
  for (int i = 0; i < 32; i += 8)
    out[(long)(n0 + ty + i) * Kd + k0 + tx] = f2b(tl[tx][ty + i]);
}

// ---- C[M][N] = A[M][K] * Bt[N][K]^T   (bf16 in, fp32 acc, OutT out) ----
template <typename OutT>
__global__ __launch_bounds__(256) void k_gemm(const u16* __restrict__ A,
                                              const u16* __restrict__ Bt,
                                              OutT* __restrict__ C,
                                              int M, int N, int K) {
  __shared__ __align__(16) u16 As[128 * 32];
  __shared__ __align__(16) u16 Bs[128 * 32];
  const int tid = threadIdx.x;
  const int wv = tid >> 6, lane = tid & 63;
  const int quad = lane >> 4, ln = lane & 15;
  const int wm = wv & 1, wn = wv >> 1;
  const long m0 = (long)blockIdx.x * 128;
  const long n0 = (long)blockIdx.y * 128;
  f32x4 acc[4][4] = {};
  for (int k0 = 0; k0 < K; k0 += 32) {
#pragma unroll
    for (int r = 0; r < 2; ++r) {
      int c = r * 256 + tid;  // chunk id: row = c>>2 (4 x 16B per 32-elem row)
      gl_lds16(A  + (m0 + (c >> 2)) * K + k0 + (c & 3) * 8, &As[(r * 256 + wv * 64) * 8]);
      gl_lds16(Bt + (n0 + (c >> 2)) * K + k0 + (c & 3) * 8, &Bs[(r * 256 + wv * 64) * 8]);
    }
    __syncthreads();
    bf16x8 af[4], bg[4];
#pragma unroll
    for (int i = 0; i < 4; ++i)
      af[i] = *(const bf16x8*)&As[(wm * 64 + i * 16 + ln) * 32 + quad * 8];
#pragma unroll
    for (int j = 0; j < 4; ++j)
      bg[j] = *(const bf16x8*)&Bs[(wn * 64 + j * 16 + ln) * 32 + quad * 8];
#pragma unroll
    for (int i = 0; i < 4; ++i)
#pragma unroll
      for (int j = 0; j < 4; ++j)
        acc[i][j] = __builtin_amdgcn_mfma_f32_16x16x32_bf16(af[i], bg[j], acc[i][j], 0, 0, 0);
    __syncthreads();
  }
#pragma unroll
  for (int i = 0; i < 4; ++i) {
    long row = m0 + wm * 64 + i * 16 + quad * 4;
#pragma unroll
    for (int j = 0; j < 4; ++j) {
      long col = n0 + wn * 64 + j * 16 + ln;
#pragma unroll
      for (int r = 0; r < 4; ++r)
        storev(&C[(row + r) * N + col], acc[i][j][r]);
    }
  }
}

// ---- RoPE + reshape (+ optional Q pre-scale): Cqkv -> out[b,head,t,d] ----
__global__ __launch_bounds__(256) void k_rope(const u16* __restrict__ C,
                                              u16* __restrict__ o,
                                              int hshift, int coloff, float qscale) {
  int idx = blockIdx.x * 256 + threadIdx.x;
  int d = idx & 63;
  int t = (idx >> 6) & (T_SEQ - 1);
  int bh = idx >> 17;
  int head = bh & ((1 << hshift) - 1);
  long inb = (long)((bh >> hshift) * T_SEQ + t) * NQKV + coloff + head * HD + d;
  float q1 = b2f(C[inb]);
  float q2 = b2f(C[inb + 64]);
  float inv = __expf(-0.14391156f * (float)d);  // 10000^(-d/64)
  float sn, cs;
  __sincosf((float)t * inv, &sn, &cs);
  long ob = ((long)bh * T_SEQ + t) * HD + d;
  o[ob]      = f2b((q1 * cs - q2 * sn) * qscale);
  o[ob + 64] = f2b((q2 * cs + q1 * sn) * qscale);
}

// ---- V columns of Cqkv -> Vt [B,KV,hd,T] ----
__global__ __launch_bounds__(256) void k_vt(const u16* __restrict__ C,
                                            u16* __restrict__ Vt) {
  __shared__ u16 tl[32][33];
  int bkv = blockIdx.z;
  int t0 = blockIdx.x * 32, d0 = blockIdx.y * 32;
  int tx = threadIdx.x, ty = threadIdx.y;
  int b = bkv >> 2, kv = bkv & 3;
#pragma unroll
  for (int i = 0; i < 32; i += 8)
    tl[ty + i][tx] = C[(long)(b * T_SEQ + t0 + ty + i) * NQKV + 2560 + kv * HD + d0 + tx];
  __syncthreads();
#pragma unroll
  for (int i = 0; i < 32; i += 8)
    Vt[((long)bkv * HD + d0 + ty + i) * T_SEQ + t0 + tx] = tl[tx][ty + i];
}

// ---- softmax update for one 16x64 score strip (log2 domain) ----
// S in MFMA C-layout: S[nt][r] = S[row=quad*4+r][col=nt*16+ln]
// l is accumulated separately via MFMA against an all-ones B fragment
// (caller); here we only rescale lacc/oacc by alpha and emit P (bf16) to Pb
// with 16B-chunk XOR swizzle: chunk (col>>3) ^ (row&7).
template <bool DIAG>
__device__ __forceinline__ void softmax_step(f32x4 (&S)[4], float (&m_i)[4],
                                             f32x4& lacc, f32x4 (&oacc)[8],
                                             u16* __restrict__ Pb,
                                             int quad, int ln, int mrow) {
  float mnew[4];
#pragma unroll
  for (int r = 0; r < 4; ++r) mnew[r] = m_i[r];
#pragma unroll
  for (int nt = 0; nt < 4; ++nt)
#pragma unroll
    for (int r = 0; r < 4; ++r) {
      float v = S[nt][r];
      if (DIAG) v = (nt * 16 + ln <= mrow + r) ? v : -1e30f;
      S[nt][r] = v;
      mnew[r] = fmaxf(mnew[r], v);
    }
#pragma unroll
  for (int off = 1; off < 16; off <<= 1)
#pragma unroll
    for (int r = 0; r < 4; ++r)
      mnew[r] = fmaxf(mnew[r], __shfl_xor(mnew[r], off, 64));
  float alpha[4];
#pragma unroll
  for (int r = 0; r < 4; ++r) {
    alpha[r] = exp2f(m_i[r] - mnew[r]);
    m_i[r] = mnew[r];
  }
#pragma unroll
  for (int r = 0; r < 4; ++r) lacc[r] *= alpha[r];
#pragma unroll
  for (int dt = 0; dt < 8; ++dt)
#pragma unroll
    for (int r = 0; r < 4; ++r) oacc[dt][r] *= alpha[r];
#pragma unroll
  for (int nt = 0; nt < 4; ++nt)
#pragma unroll
    for (int r = 0; r < 4; ++r) {
      float pv = exp2f(S[nt][r] - mnew[r]);
      int row = quad * 4 + r;
      int chnk = (nt * 2 + (ln >> 3)) ^ (row & 7);
      *(__bf16*)&Pb[row * 64 + chnk * 8 + (ln & 7)] = (__bf16)pv;
    }
}

// ---- causal GQA flash attention: pair-balanced, 8 waves/block ----
// Block p handles q-tiles {31-p, p}. Waves 0-3 own 16-row strips of the hi
// tile, waves 4-7 of the lo tile -> the two softmax dependency chains run on
// different waves (2x latency hiding vs 1 wave doing both serially).
// K/V staged once per block, shared by both tiles. l accumulated via a
// P x ones MFMA (no sum-shuffle reduction). Q is pre-scaled by
// scale*log2(e); softmax runs in exp2 domain.
__global__ __launch_bounds__(512, 4) void k_attn(const u16* __restrict__ Q,
                                                 const u16* __restrict__ Kg,
                                                 const u16* __restrict__ Vt,
                                                 u16* __restrict__ Og) {
  __shared__ __align__(16) u16 Ks[64 * 128];     // [key][hd], swizzled chunks
  __shared__ __align__(16) u16 Vs[128 * 64];     // [hd][key], swizzled chunks
  __shared__ __align__(16) u16 Ps[8][16 * 64];   // per-wave P
  const int tid = threadIdx.x;
  const int wv = tid >> 6, lane = tid & 63;
  const int quad = lane >> 4, ln = lane & 15;
  const int sw = wv & 3;                 // 16-row strip within the q-tile
  const int bh = blockIdx.y;
  const int b = bh >> 4, h = bh & 15;
  const int kvh = h >> 2;
  const int p = blockIdx.x;
  const int thi = 31 - p, tlo = p;
  const int myTile = (wv < 4) ? thi : tlo;
  const int qrow0 = myTile * 64 + sw * 16;   // q-row base of this wave's strip

  bf16x8 qf[4];
  {
    const u16* qp = Q + ((long)bh * T_SEQ + qrow0 + ln) * HD + quad * 8;
#pragma unroll
    for (int s = 0; s < 4; ++s) qf[s] = *(const bf16x8*)(qp + s * 32);
  }
  bf16x8 onesb;
#pragma unroll
  for (int i = 0; i < 8; ++i) onesb[i] = (__bf16)1.0f;

  float m_i[4];
#pragma unroll
  for (int r = 0; r < 4; ++r) m_i[r] = -1e30f;
  f32x4 lacc = {0.f, 0.f, 0.f, 0.f};
  f32x4 oacc[8] = {};

  const u16* Kb = Kg + (long)(b * NKV + kvh) * T_SEQ * HD;
  const u16* Vb = Vt + (long)(b * NKV + kvh) * HD * T_SEQ;

  for (int kt = 0; kt <= thi; ++kt) {
    const int k0 = kt * 64;
    // stage K (64x128) and V^T (128x64); global chunk choice applies the XOR
    // swizzle (LDS slot is fixed at base+lane*16 by the HW).
#pragma unroll
    for (int r = 0; r < 2; ++r) {
      int s = r * 512 + tid;
      gl_lds16(Kb + (long)(k0 + (s >> 4)) * HD + (((s & 15) ^ ((s >> 4) & 15)) << 3),
               &Ks[(r * 512 + wv * 64) * 8]);
      gl_lds16(Vb + (long)(s >> 3) * T_SEQ + k0 + (((s & 7) ^ ((s >> 3) & 7)) << 3),
               &Vs[(r * 512 + wv * 64) * 8]);
    }
    __syncthreads();
    if (kt <= myTile) {
      // S = Q K^T
      f32x4 S[4];
#pragma unroll
      for (int nt = 0; nt < 4; ++nt) {
        bf16x8 kb[4];
        const u16* kp = &Ks[(nt * 16 + ln) * 128];
#pragma unroll
        for (int ss = 0; ss < 4; ++ss)
          kb[ss] = *(const bf16x8*)(kp + (((quad + 4 * ss) ^ ln) << 3));
        f32x4 s = {0.f, 0.f, 0.f, 0.f};
#pragma unroll
        for (int ss = 0; ss < 4; ++ss)
          s = __builtin_amdgcn_mfma_f32_16x16x32_bf16(qf[ss], kb[ss], s, 0, 0, 0);
        S[nt] = s;
      }
      if (kt == myTile)
        softmax_step<true>(S, m_i, lacc, oacc, &Ps[wv][0], quad, ln, sw * 16 + quad * 4);
      else
        softmax_step<false>(S, m_i, lacc, oacc, &Ps[wv][0], quad, ln, 0);
      // drain P ds_writes before same-wave cross-lane readback
      asm volatile("s_waitcnt lgkmcnt(0)" ::: "memory");
      bf16x8 pf[2];
#pragma unroll
      for (int ss = 0; ss < 2; ++ss)
        pf[ss] = *(const bf16x8*)&Ps[wv][ln * 64 + (((ss * 4 + quad) ^ (ln & 7)) << 3)];
      // l += P . ones  (row-sum via MFMA, replaces shuffle reduction)
      lacc = __builtin_amdgcn_mfma_f32_16x16x32_bf16(pf[0], onesb, lacc, 0, 0, 0);
      lacc = __builtin_amdgcn_mfma_f32_16x16x32_bf16(pf[1], onesb, lacc, 0, 0, 0);
      // O += P V
#pragma unroll
      for (int dt = 0; dt < 8; ++dt) {
        bf16x8 vb[2];
        const u16* vp = &Vs[(dt * 16 + ln) * 64];
#pragma unroll
        for (int ss = 0; ss < 2; ++ss)
          vb[ss] = *(const bf16x8*)(vp + (((quad + 4 * ss) ^ (ln & 7)) << 3));
#pragma unroll
        for (int ss = 0; ss < 2; ++ss)
          oacc[dt] = __builtin_amdgcn_mfma_f32_16x16x32_bf16(pf[ss], vb[ss], oacc[dt], 0, 0, 0);
      }
    }
    __syncthreads();
  }
  // epilogue: normalize, store strip to attn buffer [B*T][NH*HD]
  float rl[4];
#pragma unroll
  for (int r = 0; r < 4; ++r) rl[r] = 1.f / lacc[r];
#pragma unroll
  for (int dt = 0; dt < 8; ++dt)
#pragma unroll
    for (int r = 0; r < 4; ++r) {
      long row = (long)b * T_SEQ + qrow0 + quad * 4 + r;
      Og[row * (NH * HD) + h * HD + dt * 16 + ln] = f2b(oacc[dt][r] * rl[r]);
    }
}

extern "C" void kernel_launch(void* const* d_in, const int* in_sizes, int n_in,
                              void* d_out, int out_size, void* d_ws, size_t ws_size,
                              hipStream_t stream) {
  const float* x  = (const float*)d_in[0];
  const float* Wq = (const float*)d_in[1];
  const float* Wk = (const float*)d_in[2];
  const float* Wv = (const float*)d_in[3];
  const float* Wo = (const float*)d_in[4];
  float* out = (float*)d_out;
  char* ws = (char*)d_ws;
  // workspace layout (bytes)
  u16* WT  = (u16*)(ws + 0);          // [3072][2048] bf16  (Wq^T | Wk^T | Wv^T)
  u16* Wot = (u16*)(ws + 12582912);   // [2048][2048] bf16
  u16* Cq  = (u16*)(ws + 20971520);   // [4096][3072] bf16 ; later attn [4096][2048]
  u16* Xb  = (u16*)(ws + 46137344);   // [4096][2048] bf16 ; later Q [B,NH,T,HD]
  u16* Kb  = (u16*)(ws + 62914560);   // [B,NKV,T,HD] bf16
  u16* Vtb = (u16*)(ws + 67108864);   // [B,NKV,HD,T] bf16
  u16* Qb = Xb;    // alias: Xb dead after QKV GEMM
  u16* attn = Cq;  // alias: Cqkv dead after rope/vtrans

  k_cvt_x<<<8192, 256, 0, stream>>>(x, Xb, MROWS * DM);
  k_tw<<<dim3(64, 64), dim3(32, 8), 0, stream>>>(Wq, WT, DM, 2048);
  k_tw<<<dim3(16, 64), dim3(32, 8), 0, stream>>>(Wk, WT + 2048 * 2048, DM, 512);
  k_tw<<<dim3(16, 64), dim3(32, 8), 0, stream>>>(Wv, WT + 2560 * 2048, DM, 512);
  k_tw<<<dim3(64, 64), dim3(32, 8), 0, stream>>>(Wo, Wot, DM, 2048);

  k_gemm<u16><<<dim3(32, 24), 256, 0, stream>>>(Xb, WT, Cq, MROWS, NQKV, DM);

  // Q gets softmax scale * log2(e) folded in (attention runs in exp2 domain)
  k_rope<<<16384, 256, 0, stream>>>(Cq, Qb, 4, 0, 0.12751745f);
  k_rope<<<4096, 256, 0, stream>>>(Cq, Kb, 2, 2048, 1.0f);
  k_vt<<<dim3(64, 4, 8), dim3(32, 8), 0, stream>>>(Cq, Vtb);

  k_attn<<<dim3(16, 32), 512, 0, stream>>>(Qb, Kb, Vtb, attn);

  k_gemm<float><<<dim3(32, 16), 256, 0, stream>>>(attn, Wot, out, MROWS, DM, 2048);
}

// Round 4
// 319.794 us; speedup vs baseline: 1.1412x; 1.1412x over previous
//
#include <hip/hip_runtime.h>
#include <stdint.h>

#define T_SEQ 2048
#define DM    2048
#define NH    16
#define NKV   4
#define HD    128
#define MROWS 4096          // B*T
#define NQKV  3072          // 16*128 + 4*128 + 4*128

typedef unsigned short u16;
typedef __bf16 bf16x8 __attribute__((ext_vector_type(8)));
typedef float  f32x4  __attribute__((ext_vector_type(4)));

__device__ __forceinline__ u16 f2b(float f) {
  union { float f; unsigned u; } v; v.f = f;
  return (u16)((v.u + 0x7fffu + ((v.u >> 16) & 1u)) >> 16);
}
__device__ __forceinline__ float b2f(u16 u) {
  union { unsigned u; float f; } v; v.u = ((unsigned)u) << 16;
  return v.f;
}
// async global->LDS, 16B per lane; LDS dest = wave-uniform base + lane*16
__device__ __forceinline__ void gl_lds16(const u16* g, u16* l) {
  __builtin_amdgcn_global_load_lds(
      (__attribute__((address_space(1))) void*)g,
      (__attribute__((address_space(3))) void*)l, 16, 0, 0);
}
__device__ __forceinline__ void storev(float* p, float v) { *p = v; }
__device__ __forceinline__ void storev(u16* p, float v)   { *p = f2b(v); }

// ---- fp32 -> bf16 elementwise (x) ----
__global__ __launch_bounds__(256) void k_cvt_x(const float* __restrict__ x,
                                               u16* __restrict__ o, int n) {
  int i = (blockIdx.x * 256 + threadIdx.x) * 4;
  if (i >= n) return;
  float4 v = *(const float4*)(x + i);
  ushort4 r;
  r.x = f2b(v.x); r.y = f2b(v.y); r.z = f2b(v.z); r.w = f2b(v.w);
  *(ushort4*)(o + i) = r;
}

// ---- all four weight transposes in one launch ----
// z selects: [0,64) Wq -> WT, [64,80) Wk -> WT+2048*2048,
//            [80,96) Wv -> WT+2560*2048, [96,160) Wo -> Wot. Kd=2048 always.
__global__ __launch_bounds__(256) void k_tw4(const float* __restrict__ Wq,
                                             const float* __restrict__ Wk,
                                             const float* __restrict__ Wv,
                                             const float* __restrict__ Wo,
                                             u16* __restrict__ WT,
                                             u16* __restrict__ Wot) {
  __shared__ float tl[32][33];
  int z = blockIdx.z;
  const float* in; u16* out; int Nd, xt;
  if (z < 64)      { in = Wq; out = WT;               Nd = 2048; xt = z; }
  else if (z < 80) { in = Wk; out = WT + 2048 * 2048; Nd = 512;  xt = z - 64; }
  else if (z < 96) { in = Wv; out = WT + 2560 * 2048; Nd = 512;  xt = z - 80; }
  else             { in = Wo; out = Wot;              Nd = 2048; xt = z - 96; }
  int n0 = xt * 32, k0 = blockIdx.y * 32;
  int tx = threadIdx.x, ty = threadIdx.y;
#pragma unroll
  for (int i = 0; i < 32; i += 8)
    tl[ty + i][tx] = in[(long)(k0 + ty + i) * Nd + n0 + tx];
  __syncthreads();
#pragma unroll
  for (int i = 0; i < 32; i += 8)
    out[(long)(n0 + ty + i) * 2048 + k0 + tx] = f2b(tl[tx][ty + i]);
}

// ---- C[M][N] = A[M][K] * Bt[N][K]^T   (bf16 in, fp32 acc, OutT out) ----
template <typename OutT>
__global__ __launch_bounds__(256) void k_gemm(const u16* __restrict__ A,
                                              const u16* __restrict__ Bt,
                                              OutT* __restrict__ C,
                                              int M, int N, int K) {
  __shared__ __align__(16) u16 As[128 * 32];
  __shared__ __align__(16) u16 Bs[128 * 32];
  const int tid = threadIdx.x;
  const int wv = tid >> 6, lane = tid & 63;
  const int quad = lane >> 4, ln = lane & 15;
  const int wm = wv & 1, wn = wv >> 1;
  const long m0 = (long)blockIdx.x * 128;
  const long n0 = (long)blockIdx.y * 128;
  f32x4 acc[4][4] = {};
  for (int k0 = 0; k0 < K; k0 += 32) {
#pragma unroll
    for (int r = 0; r < 2; ++r) {
      int c = r * 256 + tid;  // chunk id: row = c>>2 (4 x 16B per 32-elem row)
      gl_lds16(A  + (m0 + (c >> 2)) * K + k0 + (c & 3) * 8, &As[(r * 256 + wv * 64) * 8]);
      gl_lds16(Bt + (n0 + (c >> 2)) * K + k0 + (c & 3) * 8, &Bs[(r * 256 + wv * 64) * 8]);
    }
    __syncthreads();
    bf16x8 af[4], bg[4];
#pragma unroll
    for (int i = 0; i < 4; ++i)
      af[i] = *(const bf16x8*)&As[(wm * 64 + i * 16 + ln) * 32 + quad * 8];
#pragma unroll
    for (int j = 0; j < 4; ++j)
      bg[j] = *(const bf16x8*)&Bs[(wn * 64 + j * 16 + ln) * 32 + quad * 8];
#pragma unroll
    for (int i = 0; i < 4; ++i)
#pragma unroll
      for (int j = 0; j < 4; ++j)
        acc[i][j] = __builtin_amdgcn_mfma_f32_16x16x32_bf16(af[i], bg[j], acc[i][j], 0, 0, 0);
    __syncthreads();
  }
#pragma unroll
  for (int i = 0; i < 4; ++i) {
    long row = m0 + wm * 64 + i * 16 + quad * 4;
#pragma unroll
    for (int j = 0; j < 4; ++j) {
      long col = n0 + wn * 64 + j * 16 + ln;
#pragma unroll
      for (int r = 0; r < 4; ++r)
        storev(&C[(row + r) * N + col], acc[i][j][r]);
    }
  }
}

// ---- fused RoPE for Q (16 heads, pre-scaled) and K (4 kv heads) ----
// Q gets scale*log2(e) folded in (attention runs in exp2 domain).
__global__ __launch_bounds__(256) void k_rope2(const u16* __restrict__ C,
                                               u16* __restrict__ Qo,
                                               u16* __restrict__ Ko) {
  int idx = blockIdx.x * 256 + threadIdx.x;
  int d = idx & 63;
  int t = (idx >> 6) & (T_SEQ - 1);
  int g = idx >> 17;            // 0..39 : b*20 + hh
  int b = (g >= 20) ? 1 : 0;
  int hh = g - b * 20;
  int isQ = hh < 16;
  int head = isQ ? hh : (hh - 16);
  int coloff = isQ ? 0 : 2048;
  float qscale = isQ ? 0.12751745f : 1.0f;   // (1/sqrt(128))*log2(e)
  u16* o = isQ ? Qo : Ko;
  int nh = isQ ? NH : NKV;
  long inb = (long)(b * T_SEQ + t) * NQKV + coloff + head * HD + d;
  float q1 = b2f(C[inb]);
  float q2 = b2f(C[inb + 64]);
  float inv = __expf(-0.14391156f * (float)d);  // 10000^(-d/64)
  float sn, cs;
  __sincosf((float)t * inv, &sn, &cs);
  long ob = (((long)b * nh + head) * T_SEQ + t) * HD + d;
  o[ob]      = f2b((q1 * cs - q2 * sn) * qscale);
  o[ob + 64] = f2b((q2 * cs + q1 * sn) * qscale);
}

// ---- V columns of Cqkv -> Vt [B,KV,hd,T] ----
__global__ __launch_bounds__(256) void k_vt(const u16* __restrict__ C,
                                            u16* __restrict__ Vt) {
  __shared__ u16 tl[32][33];
  int bkv = blockIdx.z;
  int t0 = blockIdx.x * 32, d0 = blockIdx.y * 32;
  int tx = threadIdx.x, ty = threadIdx.y;
  int b = bkv >> 2, kv = bkv & 3;
#pragma unroll
  for (int i = 0; i < 32; i += 8)
    tl[ty + i][tx] = C[(long)(b * T_SEQ + t0 + ty + i) * NQKV + 2560 + kv * HD + d0 + tx];
  __syncthreads();
#pragma unroll
  for (int i = 0; i < 32; i += 8)
    Vt[((long)bkv * HD + d0 + ty + i) * T_SEQ + t0 + tx] = tl[tx][ty + i];
}

// ---- fixed-rebase P emit for one 16x64 score strip ----
// S in MFMA C-layout: S[nt][r] = S[row=quad*4+r][col=nt*16+ln].
// P = exp2(S - 8): no running max / alpha / rescale. Exact up to bf16
// rounding of P (ratios cancel in O = sum(P V)/sum(P); overflow would need
// scores ~130 sigma). Writes P (bf16) with 16B-chunk XOR swizzle.
template <bool DIAG>
__device__ __forceinline__ void p_emit(f32x4 (&S)[4], u16* __restrict__ Pb,
                                       int quad, int ln, int mrow) {
#pragma unroll
  for (int nt = 0; nt < 4; ++nt)
#pragma unroll
    for (int r = 0; r < 4; ++r) {
      float v = S[nt][r];
      if (DIAG) v = (nt * 16 + ln <= mrow + r) ? v : -1e30f;
      float pv = exp2f(v - 8.0f);
      int row = quad * 4 + r;
      int chnk = (nt * 2 + (ln >> 3)) ^ (row & 7);
      *(__bf16*)&Pb[row * 64 + chnk * 8 + (ln & 7)] = (__bf16)pv;
    }
}

// ---- causal GQA flash attention: pair-balanced, fixed-rebase softmax ----
// Block p handles q-tiles {31-p, p}: uniform 33 strip-tiles of work. Each
// wave owns a 16-row strip of BOTH tiles (ILP: two independent chains in one
// wave); K/V LDS tiles and register fragments shared between strips. l via
// P x ones MFMA. Iterations are independent accumulations -> GEMM-like
// pipelining. All LDS uses 16B-chunk XOR swizzle (0 bank conflicts, r2).
__global__ __launch_bounds__(256, 2) void k_attn(const u16* __restrict__ Q,
                                                 const u16* __restrict__ Kg,
                                                 const u16* __restrict__ Vt,
                                                 u16* __restrict__ Og) {
  __shared__ __align__(16) u16 Ks[64 * 128];     // [key][hd], swizzled chunks
  __shared__ __align__(16) u16 Vs[128 * 64];     // [hd][key], swizzled chunks
  __shared__ __align__(16) u16 Ps[4][2][16 * 64]; // per-wave, per-strip P
  const int tid = threadIdx.x;
  const int wv = tid >> 6, lane = tid & 63;
  const int quad = lane >> 4, ln = lane & 15;
  const int bh = blockIdx.y;
  const int b = bh >> 4, h = bh & 15;
  const int kvh = h >> 2;
  const int p = blockIdx.x;
  const int thi = 31 - p, tlo = p;
  const int qhi = thi * 64 + wv * 16;   // global q-row base, hi strip
  const int qlo = tlo * 64 + wv * 16;

  bf16x8 qfh[4], qfl[4];
  {
    const u16* qp = Q + ((long)bh * T_SEQ + qhi + ln) * HD + quad * 8;
#pragma unroll
    for (int s = 0; s < 4; ++s) qfh[s] = *(const bf16x8*)(qp + s * 32);
    qp = Q + ((long)bh * T_SEQ + qlo + ln) * HD + quad * 8;
#pragma unroll
    for (int s = 0; s < 4; ++s) qfl[s] = *(const bf16x8*)(qp + s * 32);
  }
  bf16x8 onesb;
#pragma unroll
  for (int i = 0; i < 8; ++i) onesb[i] = (__bf16)1.0f;

  f32x4 lh = {0.f, 0.f, 0.f, 0.f}, ll = {0.f, 0.f, 0.f, 0.f};
  f32x4 oh[8] = {}, ol[8] = {};

  const u16* Kb = Kg + (long)(b * NKV + kvh) * T_SEQ * HD;
  const u16* Vb = Vt + (long)(b * NKV + kvh) * HD * T_SEQ;

  for (int kt = 0; kt <= thi; ++kt) {
    const int k0 = kt * 64;
    // stage K (64x128) and V^T (128x64); global chunk choice applies the XOR
    // swizzle (LDS slot fixed at base+lane*16 by HW).
#pragma unroll
    for (int r = 0; r < 4; ++r) {
      int s = r * 256 + tid;
      gl_lds16(Kb + (long)(k0 + (s >> 4)) * HD + (((s & 15) ^ ((s >> 4) & 15)) << 3),
               &Ks[(r * 256 + wv * 64) * 8]);
      gl_lds16(Vb + (long)(s >> 3) * T_SEQ + k0 + (((s & 7) ^ ((s >> 3) & 7)) << 3),
               &Vs[(r * 256 + wv * 64) * 8]);
    }
    __syncthreads();
    const bool lo_act = (kt <= tlo);
    // S = Q K^T for both strips, sharing K fragments
    f32x4 Sh[4], Sl[4];
#pragma unroll
    for (int nt = 0; nt < 4; ++nt) {
      bf16x8 kb[4];
      const u16* kp = &Ks[(nt * 16 + ln) * 128];
#pragma unroll
      for (int ss = 0; ss < 4; ++ss)
        kb[ss] = *(const bf16x8*)(kp + (((quad + 4 * ss) ^ ln) << 3));
      f32x4 s = {0.f, 0.f, 0.f, 0.f};
#pragma unroll
      for (int ss = 0; ss < 4; ++ss)
        s = __builtin_amdgcn_mfma_f32_16x16x32_bf16(qfh[ss], kb[ss], s, 0, 0, 0);
      Sh[nt] = s;
      if (lo_act) {
        f32x4 t = {0.f, 0.f, 0.f, 0.f};
#pragma unroll
        for (int ss = 0; ss < 4; ++ss)
          t = __builtin_amdgcn_mfma_f32_16x16x32_bf16(qfl[ss], kb[ss], t, 0, 0, 0);
        Sl[nt] = t;
      }
    }
    if (kt == thi) p_emit<true>(Sh, &Ps[wv][0][0], quad, ln, wv * 16 + quad * 4);
    else           p_emit<false>(Sh, &Ps[wv][0][0], quad, ln, 0);
    if (lo_act) {
      if (kt == tlo) p_emit<true>(Sl, &Ps[wv][1][0], quad, ln, wv * 16 + quad * 4);
      else           p_emit<false>(Sl, &Ps[wv][1][0], quad, ln, 0);
    }
    // drain P ds_writes before same-wave cross-lane readback
    asm volatile("s_waitcnt lgkmcnt(0)" ::: "memory");
    bf16x8 pfh[2], pfl[2];
#pragma unroll
    for (int ss = 0; ss < 2; ++ss)
      pfh[ss] = *(const bf16x8*)&Ps[wv][0][ln * 64 + (((ss * 4 + quad) ^ (ln & 7)) << 3)];
    if (lo_act) {
#pragma unroll
      for (int ss = 0; ss < 2; ++ss)
        pfl[ss] = *(const bf16x8*)&Ps[wv][1][ln * 64 + (((ss * 4 + quad) ^ (ln & 7)) << 3)];
    }
    // l += P . ones (row-sums via MFMA; no shuffle reduction)
    lh = __builtin_amdgcn_mfma_f32_16x16x32_bf16(pfh[0], onesb, lh, 0, 0, 0);
    lh = __builtin_amdgcn_mfma_f32_16x16x32_bf16(pfh[1], onesb, lh, 0, 0, 0);
    if (lo_act) {
      ll = __builtin_amdgcn_mfma_f32_16x16x32_bf16(pfl[0], onesb, ll, 0, 0, 0);
      ll = __builtin_amdgcn_mfma_f32_16x16x32_bf16(pfl[1], onesb, ll, 0, 0, 0);
    }
    // O += P V, sharing V fragments between strips
#pragma unroll
    for (int dt = 0; dt < 8; ++dt) {
      bf16x8 vb[2];
      const u16* vp = &Vs[(dt * 16 + ln) * 64];
#pragma unroll
      for (int ss = 0; ss < 2; ++ss)
        vb[ss] = *(const bf16x8*)(vp + (((quad + 4 * ss) ^ (ln & 7)) << 3));
#pragma unroll
      for (int ss = 0; ss < 2; ++ss)
        oh[dt] = __builtin_amdgcn_mfma_f32_16x16x32_bf16(pfh[ss], vb[ss], oh[dt], 0, 0, 0);
      if (lo_act) {
#pragma unroll
        for (int ss = 0; ss < 2; ++ss)
          ol[dt] = __builtin_amdgcn_mfma_f32_16x16x32_bf16(pfl[ss], vb[ss], ol[dt], 0, 0, 0);
      }
    }
    __syncthreads();
  }
  // epilogue: normalize, store both strips to attn buffer [B*T][NH*HD]
  float rh[4], rl[4];
#pragma unroll
  for (int r = 0; r < 4; ++r) { rh[r] = 1.f / lh[r]; rl[r] = 1.f / ll[r]; }
#pragma unroll
  for (int dt = 0; dt < 8; ++dt)
#pragma unroll
    for (int r = 0; r < 4; ++r) {
      long rowh = (long)b * T_SEQ + qhi + quad * 4 + r;
      long rowl = (long)b * T_SEQ + qlo + quad * 4 + r;
      Og[rowh * (NH * HD) + h * HD + dt * 16 + ln] = f2b(oh[dt][r] * rh[r]);
      Og[rowl * (NH * HD) + h * HD + dt * 16 + ln] = f2b(ol[dt][r] * rl[r]);
    }
}

extern "C" void kernel_launch(void* const* d_in, const int* in_sizes, int n_in,
                              void* d_out, int out_size, void* d_ws, size_t ws_size,
                              hipStream_t stream) {
  const float* x  = (const float*)d_in[0];
  const float* Wq = (const float*)d_in[1];
  const float* Wk = (const float*)d_in[2];
  const float* Wv = (const float*)d_in[3];
  const float* Wo = (const float*)d_in[4];
  float* out = (float*)d_out;
  char* ws = (char*)d_ws;
  // workspace layout (bytes)
  u16* WT  = (u16*)(ws + 0);          // [3072][2048] bf16  (Wq^T | Wk^T | Wv^T)
  u16* Wot = (u16*)(ws + 12582912);   // [2048][2048] bf16
  u16* Cq  = (u16*)(ws + 20971520);   // [4096][3072] bf16 ; later attn [4096][2048]
  u16* Xb  = (u16*)(ws + 46137344);   // [4096][2048] bf16 ; later Q [B,NH,T,HD]
  u16* Kb  = (u16*)(ws + 62914560);   // [B,NKV,T,HD] bf16
  u16* Vtb = (u16*)(ws + 67108864);   // [B,NKV,HD,T] bf16
  u16* Qb = Xb;    // alias: Xb dead after QKV GEMM
  u16* attn = Cq;  // alias: Cqkv dead after rope/vtrans

  k_cvt_x<<<8192, 256, 0, stream>>>(x, Xb, MROWS * DM);
  k_tw4<<<dim3(1, 64, 160), dim3(32, 8), 0, stream>>>(Wq, Wk, Wv, Wo, WT, Wot);

  k_gemm<u16><<<dim3(32, 24), 256, 0, stream>>>(Xb, WT, Cq, MROWS, NQKV, DM);

  k_rope2<<<20480, 256, 0, stream>>>(Cq, Qb, Kb);
  k_vt<<<dim3(64, 4, 8), dim3(32, 8), 0, stream>>>(Cq, Vtb);

  k_attn<<<dim3(16, 32), 256, 0, stream>>>(Qb, Kb, Vtb, attn);

  k_gemm<float><<<dim3(32, 16), 256, 0, stream>>>(attn, Wot, out, MROWS, DM, 2048);
}

// Round 5
// 312.506 us; speedup vs baseline: 1.1678x; 1.0233x over previous
//
#include <hip/hip_runtime.h>
#include <stdint.h>

#define T_SEQ 2048
#define DM    2048
#define NH    16
#define NKV   4
#define HD    128
#define MROWS 4096          // B*T
#define NQKV  3072          // 16*128 + 4*128 + 4*128

typedef unsigned short u16;
typedef __bf16 bf16x8 __attribute__((ext_vector_type(8)));
typedef float  f32x4  __attribute__((ext_vector_type(4)));

__device__ __forceinline__ u16 f2b(float f) {
  union { float f; unsigned u; } v; v.f = f;
  return (u16)((v.u + 0x7fffu + ((v.u >> 16) & 1u)) >> 16);
}
__device__ __forceinline__ float b2f(u16 u) {
  union { unsigned u; float f; } v; v.u = ((unsigned)u) << 16;
  return v.f;
}
// async global->LDS, 16B per lane; LDS dest = wave-uniform base + lane*16
__device__ __forceinline__ void gl_lds16(const u16* g, u16* l) {
  __builtin_amdgcn_global_load_lds(
      (__attribute__((address_space(1))) void*)g,
      (__attribute__((address_space(3))) void*)l, 16, 0, 0);
}
__device__ __forceinline__ void storev(float* p, float v) { *p = v; }
__device__ __forceinline__ void storev(u16* p, float v)   { *p = f2b(v); }

// ---- fp32 -> bf16 elementwise (x) ----
__global__ __launch_bounds__(256) void k_cvt_x(const float* __restrict__ x,
                                               u16* __restrict__ o, int n) {
  int i = (blockIdx.x * 256 + threadIdx.x) * 4;
  if (i >= n) return;
  float4 v = *(const float4*)(x + i);
  ushort4 r;
  r.x = f2b(v.x); r.y = f2b(v.y); r.z = f2b(v.z); r.w = f2b(v.w);
  *(ushort4*)(o + i) = r;
}

// ---- all four weight transposes in one launch ----
// z selects: [0,64) Wq -> WT, [64,80) Wk -> WT+2048*2048,
//            [80,96) Wv -> WT+2560*2048, [96,160) Wo -> Wot. Kd=2048 always.
__global__ __launch_bounds__(256) void k_tw4(const float* __restrict__ Wq,
                                             const float* __restrict__ Wk,
                                             const float* __restrict__ Wv,
                                             const float* __restrict__ Wo,
                                             u16* __restrict__ WT,
                                             u16* __restrict__ Wot) {
  __shared__ float tl[32][33];
  int z = blockIdx.z;
  const float* in; u16* out; int Nd, xt;
  if (z < 64)      { in = Wq; out = WT;               Nd = 2048; xt = z; }
  else if (z < 80) { in = Wk; out = WT + 2048 * 2048; Nd = 512;  xt = z - 64; }
  else if (z < 96) { in = Wv; out = WT + 2560 * 2048; Nd = 512;  xt = z - 80; }
  else             { in = Wo; out = Wot;              Nd = 2048; xt = z - 96; }
  int n0 = xt * 32, k0 = blockIdx.y * 32;
  int tx = threadIdx.x, ty = threadIdx.y;
#pragma unroll
  for (int i = 0; i < 32; i += 8)
    tl[ty + i][tx] = in[(long)(k0 + ty + i) * Nd + n0 + tx];
  __syncthreads();
#pragma unroll
  for (int i = 0; i < 32; i += 8)
    out[(long)(n0 + ty + i) * 2048 + k0 + tx] = f2b(tl[tx][ty + i]);
}

// ---- C[M][N] = A[M][K] * Bt[N][K]^T   (bf16 in, fp32 acc, OutT out) ----
// m97 structure + 16B-chunk XOR swizzle on As/Bs:
//   LDS rows are 32 elems = 4 chunks of 16B. Linear LDS chunk s holds global
//   chunk col (s&3)^((s>>3)&3) of row s>>2; fragment read of (row R, chunk
//   quad) is at chunk quad^((R>>1)&3). Bank-quartet slot (4R+chunk)%8 then
//   covers all 8 slots exactly twice per 16 lanes -> 2-way (free) instead of
//   the unswizzled 8-way (2.94x, m136). r4 measured 6.29e6 conflicts/dispatch.
template <typename OutT>
__global__ __launch_bounds__(256) void k_gemm(const u16* __restrict__ A,
                                              const u16* __restrict__ Bt,
                                              OutT* __restrict__ C,
                                              int M, int N, int K) {
  __shared__ __align__(16) u16 As[128 * 32];
  __shared__ __align__(16) u16 Bs[128 * 32];
  const int tid = threadIdx.x;
  const int wv = tid >> 6, lane = tid & 63;
  const int quad = lane >> 4, ln = lane & 15;
  const int wm = wv & 1, wn = wv >> 1;
  const int rchnk = quad ^ ((ln >> 1) & 3);   // swizzled chunk col for reads
  const long m0 = (long)blockIdx.x * 128;
  const long n0 = (long)blockIdx.y * 128;
  f32x4 acc[4][4] = {};
  for (int k0 = 0; k0 < K; k0 += 32) {
#pragma unroll
    for (int r = 0; r < 2; ++r) {
      int c = r * 256 + tid;  // linear LDS chunk id; row = c>>2
      int gc = (c & 3) ^ ((c >> 3) & 3);  // swizzled global chunk col
      gl_lds16(A  + (m0 + (c >> 2)) * K + k0 + gc * 8, &As[(r * 256 + wv * 64) * 8]);
      gl_lds16(Bt + (n0 + (c >> 2)) * K + k0 + gc * 8, &Bs[(r * 256 + wv * 64) * 8]);
    }
    __syncthreads();
    bf16x8 af[4], bg[4];
#pragma unroll
    for (int i = 0; i < 4; ++i)
      af[i] = *(const bf16x8*)&As[(wm * 64 + i * 16 + ln) * 32 + rchnk * 8];
#pragma unroll
    for (int j = 0; j < 4; ++j)
      bg[j] = *(const bf16x8*)&Bs[(wn * 64 + j * 16 + ln) * 32 + rchnk * 8];
#pragma unroll
    for (int i = 0; i < 4; ++i)
#pragma unroll
      for (int j = 0; j < 4; ++j)
        acc[i][j] = __builtin_amdgcn_mfma_f32_16x16x32_bf16(af[i], bg[j], acc[i][j], 0, 0, 0);
    __syncthreads();
  }
#pragma unroll
  for (int i = 0; i < 4; ++i) {
    long row = m0 + wm * 64 + i * 16 + quad * 4;
#pragma unroll
    for (int j = 0; j < 4; ++j) {
      long col = n0 + wn * 64 + j * 16 + ln;
#pragma unroll
      for (int r = 0; r < 4; ++r)
        storev(&C[(row + r) * N + col], acc[i][j][r]);
    }
  }
}

// ---- fused RoPE for Q (16 heads, pre-scaled) and K (4 kv heads) ----
// Q gets scale*log2(e) folded in (attention runs in exp2 domain).
__global__ __launch_bounds__(256) void k_rope2(const u16* __restrict__ C,
                                               u16* __restrict__ Qo,
                                               u16* __restrict__ Ko) {
  int idx = blockIdx.x * 256 + threadIdx.x;
  int d = idx & 63;
  int t = (idx >> 6) & (T_SEQ - 1);
  int g = idx >> 17;            // 0..39 : b*20 + hh
  int b = (g >= 20) ? 1 : 0;
  int hh = g - b * 20;
  int isQ = hh < 16;
  int head = isQ ? hh : (hh - 16);
  int coloff = isQ ? 0 : 2048;
  float qscale = isQ ? 0.12751745f : 1.0f;   // (1/sqrt(128))*log2(e)
  u16* o = isQ ? Qo : Ko;
  int nh = isQ ? NH : NKV;
  long inb = (long)(b * T_SEQ + t) * NQKV + coloff + head * HD + d;
  float q1 = b2f(C[inb]);
  float q2 = b2f(C[inb + 64]);
  float inv = __expf(-0.14391156f * (float)d);  // 10000^(-d/64)
  float sn, cs;
  __sincosf((float)t * inv, &sn, &cs);
  long ob = (((long)b * nh + head) * T_SEQ + t) * HD + d;
  o[ob]      = f2b((q1 * cs - q2 * sn) * qscale);
  o[ob + 64] = f2b((q2 * cs + q1 * sn) * qscale);
}

// ---- V columns of Cqkv -> Vt [B,KV,hd,T] ----
__global__ __launch_bounds__(256) void k_vt(const u16* __restrict__ C,
                                            u16* __restrict__ Vt) {
  __shared__ u16 tl[32][33];
  int bkv = blockIdx.z;
  int t0 = blockIdx.x * 32, d0 = blockIdx.y * 32;
  int tx = threadIdx.x, ty = threadIdx.y;
  int b = bkv >> 2, kv = bkv & 3;
#pragma unroll
  for (int i = 0; i < 32; i += 8)
    tl[ty + i][tx] = C[(long)(b * T_SEQ + t0 + ty + i) * NQKV + 2560 + kv * HD + d0 + tx];
  __syncthreads();
#pragma unroll
  for (int i = 0; i < 32; i += 8)
    Vt[((long)bkv * HD + d0 + ty + i) * T_SEQ + t0 + tx] = tl[tx][ty + i];
}

// ---- fixed-rebase P emit for one 16x64 score strip ----
// S in MFMA C-layout: S[nt][r] = S[row=quad*4+r][col=nt*16+ln].
// P = exp2(S - 8): no running max / alpha / rescale. Exact up to bf16
// rounding of P (ratios cancel in O = sum(P V)/sum(P); overflow would need
// scores ~130 sigma). Writes P (bf16) with 16B-chunk XOR swizzle.
template <bool DIAG>
__device__ __forceinline__ void p_emit(f32x4 (&S)[4], u16* __restrict__ Pb,
                                       int quad, int ln, int mrow) {
#pragma unroll
  for (int nt = 0; nt < 4; ++nt)
#pragma unroll
    for (int r = 0; r < 4; ++r) {
      float v = S[nt][r];
      if (DIAG) v = (nt * 16 + ln <= mrow + r) ? v : -1e30f;
      float pv = exp2f(v - 8.0f);
      int row = quad * 4 + r;
      int chnk = (nt * 2 + (ln >> 3)) ^ (row & 7);
      *(__bf16*)&Pb[row * 64 + chnk * 8 + (ln & 7)] = (__bf16)pv;
    }
}

// ---- causal GQA flash attention: pair-balanced, fixed-rebase softmax ----
// Block p handles q-tiles {31-p, p}: uniform 33 strip-tiles of work. Each
// wave owns a 16-row strip of BOTH tiles (ILP: two independent chains in one
// wave); K/V LDS tiles and register fragments shared between strips. l via
// P x ones MFMA. Iterations are independent accumulations -> GEMM-like
// pipelining. All LDS uses 16B-chunk XOR swizzle (0 bank conflicts, r2).
__global__ __launch_bounds__(256, 2) void k_attn(const u16* __restrict__ Q,
                                                 const u16* __restrict__ Kg,
                                                 const u16* __restrict__ Vt,
                                                 u16* __restrict__ Og) {
  __shared__ __align__(16) u16 Ks[64 * 128];     // [key][hd], swizzled chunks
  __shared__ __align__(16) u16 Vs[128 * 64];     // [hd][key], swizzled chunks
  __shared__ __align__(16) u16 Ps[4][2][16 * 64]; // per-wave, per-strip P
  const int tid = threadIdx.x;
  const int wv = tid >> 6, lane = tid & 63;
  const int quad = lane >> 4, ln = lane & 15;
  const int bh = blockIdx.y;
  const int b = bh >> 4, h = bh & 15;
  const int kvh = h >> 2;
  const int p = blockIdx.x;
  const int thi = 31 - p, tlo = p;
  const int qhi = thi * 64 + wv * 16;   // global q-row base, hi strip
  const int qlo = tlo * 64 + wv * 16;

  bf16x8 qfh[4], qfl[4];
  {
    const u16* qp = Q + ((long)bh * T_SEQ + qhi + ln) * HD + quad * 8;
#pragma unroll
    for (int s = 0; s < 4; ++s) qfh[s] = *(const bf16x8*)(qp + s * 32);
    qp = Q + ((long)bh * T_SEQ + qlo + ln) * HD + quad * 8;
#pragma unroll
    for (int s = 0; s < 4; ++s) qfl[s] = *(const bf16x8*)(qp + s * 32);
  }
  bf16x8 onesb;
#pragma unroll
  for (int i = 0; i < 8; ++i) onesb[i] = (__bf16)1.0f;

  f32x4 lh = {0.f, 0.f, 0.f, 0.f}, ll = {0.f, 0.f, 0.f, 0.f};
  f32x4 oh[8] = {}, ol[8] = {};

  const u16* Kb = Kg + (long)(b * NKV + kvh) * T_SEQ * HD;
  const u16* Vb = Vt + (long)(b * NKV + kvh) * HD * T_SEQ;

  for (int kt = 0; kt <= thi; ++kt) {
    const int k0 = kt * 64;
    // stage K (64x128) and V^T (128x64); global chunk choice applies the XOR
    // swizzle (LDS slot fixed at base+lane*16 by HW).
#pragma unroll
    for (int r = 0; r < 4; ++r) {
      int s = r * 256 + tid;
      gl_lds16(Kb + (long)(k0 + (s >> 4)) * HD + (((s & 15) ^ ((s >> 4) & 15)) << 3),
               &Ks[(r * 256 + wv * 64) * 8]);
      gl_lds16(Vb + (long)(s >> 3) * T_SEQ + k0 + (((s & 7) ^ ((s >> 3) & 7)) << 3),
               &Vs[(r * 256 + wv * 64) * 8]);
    }
    __syncthreads();
    const bool lo_act = (kt <= tlo);
    // S = Q K^T for both strips, sharing K fragments
    f32x4 Sh[4], Sl[4];
#pragma unroll
    for (int nt = 0; nt < 4; ++nt) {
      bf16x8 kb[4];
      const u16* kp = &Ks[(nt * 16 + ln) * 128];
#pragma unroll
      for (int ss = 0; ss < 4; ++ss)
        kb[ss] = *(const bf16x8*)(kp + (((quad + 4 * ss) ^ ln) << 3));
      f32x4 s = {0.f, 0.f, 0.f, 0.f};
#pragma unroll
      for (int ss = 0; ss < 4; ++ss)
        s = __builtin_amdgcn_mfma_f32_16x16x32_bf16(qfh[ss], kb[ss], s, 0, 0, 0);
      Sh[nt] = s;
      if (lo_act) {
        f32x4 t = {0.f, 0.f, 0.f, 0.f};
#pragma unroll
        for (int ss = 0; ss < 4; ++ss)
          t = __builtin_amdgcn_mfma_f32_16x16x32_bf16(qfl[ss], kb[ss], t, 0, 0, 0);
        Sl[nt] = t;
      }
    }
    if (kt == thi) p_emit<true>(Sh, &Ps[wv][0][0], quad, ln, wv * 16 + quad * 4);
    else           p_emit<false>(Sh, &Ps[wv][0][0], quad, ln, 0);
    if (lo_act) {
      if (kt == tlo) p_emit<true>(Sl, &Ps[wv][1][0], quad, ln, wv * 16 + quad * 4);
      else           p_emit<false>(Sl, &Ps[wv][1][0], quad, ln, 0);
    }
    // drain P ds_writes before same-wave cross-lane readback
    asm volatile("s_waitcnt lgkmcnt(0)" ::: "memory");
    bf16x8 pfh[2], pfl[2];
#pragma unroll
    for (int ss = 0; ss < 2; ++ss)
      pfh[ss] = *(const bf16x8*)&Ps[wv][0][ln * 64 + (((ss * 4 + quad) ^ (ln & 7)) << 3)];
    if (lo_act) {
#pragma unroll
      for (int ss = 0; ss < 2; ++ss)
        pfl[ss] = *(const bf16x8*)&Ps[wv][1][ln * 64 + (((ss * 4 + quad) ^ (ln & 7)) << 3)];
    }
    // l += P . ones (row-sums via MFMA; no shuffle reduction)
    lh = __builtin_amdgcn_mfma_f32_16x16x32_bf16(pfh[0], onesb, lh, 0, 0, 0);
    lh = __builtin_amdgcn_mfma_f32_16x16x32_bf16(pfh[1], onesb, lh, 0, 0, 0);
    if (lo_act) {
      ll = __builtin_amdgcn_mfma_f32_16x16x32_bf16(pfl[0], onesb, ll, 0, 0, 0);
      ll = __builtin_amdgcn_mfma_f32_16x16x32_bf16(pfl[1], onesb, ll, 0, 0, 0);
    }
    // O += P V, sharing V fragments between strips
#pragma unroll
    for (int dt = 0; dt < 8; ++dt) {
      bf16x8 vb[2];
      const u16* vp = &Vs[(dt * 16 + ln) * 64];
#pragma unroll
      for (int ss = 0; ss < 2; ++ss)
        vb[ss] = *(const bf16x8*)(vp + (((quad + 4 * ss) ^ (ln & 7)) << 3));
#pragma unroll
      for (int ss = 0; ss < 2; ++ss)
        oh[dt] = __builtin_amdgcn_mfma_f32_16x16x32_bf16(pfh[ss], vb[ss], oh[dt], 0, 0, 0);
      if (lo_act) {
#pragma unroll
        for (int ss = 0; ss < 2; ++ss)
          ol[dt] = __builtin_amdgcn_mfma_f32_16x16x32_bf16(pfl[ss], vb[ss], ol[dt], 0, 0, 0);
      }
    }
    __syncthreads();
  }
  // epilogue: normalize, store both strips to attn buffer [B*T][NH*HD]
  float rh[4], rl[4];
#pragma unroll
  for (int r = 0; r < 4; ++r) { rh[r] = 1.f / lh[r]; rl[r] = 1.f / ll[r]; }
#pragma unroll
  for (int dt = 0; dt < 8; ++dt)
#pragma unroll
    for (int r = 0; r < 4; ++r) {
      long rowh = (long)b * T_SEQ + qhi + quad * 4 + r;
      long rowl = (long)b * T_SEQ + qlo + quad * 4 + r;
      Og[rowh * (NH * HD) + h * HD + dt * 16 + ln] = f2b(oh[dt][r] * rh[r]);
      Og[rowl * (NH * HD) + h * HD + dt * 16 + ln] = f2b(ol[dt][r] * rl[r]);
    }
}

extern "C" void kernel_launch(void* const* d_in, const int* in_sizes, int n_in,
                              void* d_out, int out_size, void* d_ws, size_t ws_size,
                              hipStream_t stream) {
  const float* x  = (const float*)d_in[0];
  const float* Wq = (const float*)d_in[1];
  const float* Wk = (const float*)d_in[2];
  const float* Wv = (const float*)d_in[3];
  const float* Wo = (const float*)d_in[4];
  float* out = (float*)d_out;
  char* ws = (char*)d_ws;
  // workspace layout (bytes)
  u16* WT  = (u16*)(ws + 0);          // [3072][2048] bf16  (Wq^T | Wk^T | Wv^T)
  u16* Wot = (u16*)(ws + 12582912);   // [2048][2048] bf16
  u16* Cq  = (u16*)(ws + 20971520);   // [4096][3072] bf16 ; later attn [4096][2048]
  u16* Xb  = (u16*)(ws + 46137344);   // [4096][2048] bf16 ; later Q [B,NH,T,HD]
  u16* Kb  = (u16*)(ws + 62914560);   // [B,NKV,T,HD] bf16
  u16* Vtb = (u16*)(ws + 67108864);   // [B,NKV,HD,T] bf16
  u16* Qb = Xb;    // alias: Xb dead after QKV GEMM
  u16* attn = Cq;  // alias: Cqkv dead after rope/vtrans

  k_cvt_x<<<8192, 256, 0, stream>>>(x, Xb, MROWS * DM);
  k_tw4<<<dim3(1, 64, 160), dim3(32, 8), 0, stream>>>(Wq, Wk, Wv, Wo, WT, Wot);

  k_gemm<u16><<<dim3(32, 24), 256, 0, stream>>>(Xb, WT, Cq, MROWS, NQKV, DM);

  k_rope2<<<20480, 256, 0, stream>>>(Cq, Qb, Kb);
  k_vt<<<dim3(64, 4, 8), dim3(32, 8), 0, stream>>>(Cq, Vtb);

  k_attn<<<dim3(16, 32), 256, 0, stream>>>(Qb, Kb, Vtb, attn);

  k_gemm<float><<<dim3(32, 16), 256, 0, stream>>>(attn, Wot, out, MROWS, DM, 2048);
}